// Round 1
// baseline (203.243 us; speedup 1.0000x reference)
//
#include <hip/hip_runtime.h>

namespace {

constexpr int S   = 32;    // neighbors
constexpr int F   = 128;   // features
constexpr int BR  = 32;    // rows per block
constexpr int TPB = 256;

__global__ __launch_bounds__(TPB) void fused_median_gemm(
    const float* __restrict__ x,
    const float* __restrict__ neigh,
    const float* __restrict__ Ks,
    const float* __restrict__ Kn,
    const float* __restrict__ bias,
    float* __restrict__ out,
    int N)
{
    __shared__ __align__(16) float xs[BR][F];   // staged x rows (16 KB)
    __shared__ __align__(16) float ms[BR][F];   // medians      (16 KB)

    const int tid  = threadIdx.x;
    const int row0 = blockIdx.x * BR;

    // ---------------- Phase 1: median (rank 16 of 32) + x staging ----------------
    {
        const int f  = tid & (F - 1);
        const int rp = tid >> 7;               // 0..1
#pragma unroll 1
        for (int i = 0; i < BR; i += 2) {
            const int rl = i + rp;
            int row = row0 + rl;
            if (row > N - 1) row = N - 1;      // clamp tail (harmless re-read)
            const float* base = neigh + (size_t)row * (S * F) + f;
            float v[S];
#pragma unroll
            for (int s = 0; s < S; ++s) v[s] = base[(size_t)s * F];

            // bitonic sort, ascending (fully unrolled -> 240 min/max pairs)
#pragma unroll
            for (int k = 2; k <= S; k <<= 1) {
#pragma unroll
                for (int j = k >> 1; j > 0; j >>= 1) {
#pragma unroll
                    for (int a = 0; a < S; ++a) {
                        const int b = a ^ j;
                        if (b > a) {
                            const bool up = (a & k) == 0;
                            const float lo = fminf(v[a], v[b]);
                            const float hi = fmaxf(v[a], v[b]);
                            v[a] = up ? lo : hi;
                            v[b] = up ? hi : lo;
                        }
                    }
                }
            }
            ms[rl][f] = v[16];                 // n = S//2 + S%2 = 16 (0-indexed)
            xs[rl][f] = x[(size_t)row * F + f];
        }
    }
    __syncthreads();

    // ---------------- Phase 2: dual GEMM (self | neigh), bias, relu ----------------
    const int tu   = tid & 31;                 // output-col group: cols tu*8 .. tu*8+7
    const int tr   = tid >> 5;                 // 0..7, rows tr*4 .. tr*4+3
    const int ucol = tu * 8;
    const bool self_half = (tu < 16);
    const float* __restrict__ W = self_half ? Ks : Kn;
    const int ul = self_half ? ucol : (ucol - 128);
    const float* lin = self_half ? &xs[0][0] : &ms[0][0];  // stays LDS addrspace

    float4 acc[4][2];
#pragma unroll
    for (int r = 0; r < 4; ++r) {
        acc[r][0] = float4{0.f, 0.f, 0.f, 0.f};
        acc[r][1] = float4{0.f, 0.f, 0.f, 0.f};
    }

    for (int f0 = 0; f0 < F; f0 += 4) {
        float4 wv[4][2];
#pragma unroll
        for (int df = 0; df < 4; ++df) {
            wv[df][0] = *(const float4*)&W[(f0 + df) * 128 + ul];
            wv[df][1] = *(const float4*)&W[(f0 + df) * 128 + ul + 4];
        }
        float4 xv[4];
#pragma unroll
        for (int r = 0; r < 4; ++r)
            xv[r] = *(const float4*)&lin[(tr * 4 + r) * F + f0];

#pragma unroll
        for (int r = 0; r < 4; ++r) {
            const float xc[4] = {xv[r].x, xv[r].y, xv[r].z, xv[r].w};
#pragma unroll
            for (int df = 0; df < 4; ++df) {
#pragma unroll
                for (int h = 0; h < 2; ++h) {
                    acc[r][h].x = fmaf(xc[df], wv[df][h].x, acc[r][h].x);
                    acc[r][h].y = fmaf(xc[df], wv[df][h].y, acc[r][h].y);
                    acc[r][h].z = fmaf(xc[df], wv[df][h].z, acc[r][h].z);
                    acc[r][h].w = fmaf(xc[df], wv[df][h].w, acc[r][h].w);
                }
            }
        }
    }

    const float4 bv0 = *(const float4*)&bias[ucol];
    const float4 bv1 = *(const float4*)&bias[ucol + 4];
#pragma unroll
    for (int r = 0; r < 4; ++r) {
        const int row = row0 + tr * 4 + r;
        if (row < N) {
            float4 o0, o1;
            o0.x = fmaxf(acc[r][0].x + bv0.x, 0.f);
            o0.y = fmaxf(acc[r][0].y + bv0.y, 0.f);
            o0.z = fmaxf(acc[r][0].z + bv0.z, 0.f);
            o0.w = fmaxf(acc[r][0].w + bv0.w, 0.f);
            o1.x = fmaxf(acc[r][1].x + bv1.x, 0.f);
            o1.y = fmaxf(acc[r][1].y + bv1.y, 0.f);
            o1.z = fmaxf(acc[r][1].z + bv1.z, 0.f);
            o1.w = fmaxf(acc[r][1].w + bv1.w, 0.f);
            *(float4*)&out[(size_t)row * 256 + ucol]     = o0;
            *(float4*)&out[(size_t)row * 256 + ucol + 4] = o1;
        }
    }
}

} // namespace

extern "C" void kernel_launch(void* const* d_in, const int* in_sizes, int n_in,
                              void* d_out, int out_size, void* d_ws, size_t ws_size,
                              hipStream_t stream) {
    const float* x     = (const float*)d_in[0];
    const float* neigh = (const float*)d_in[1];
    const float* Ks    = (const float*)d_in[2];
    const float* Kn    = (const float*)d_in[3];
    const float* bias  = (const float*)d_in[4];
    float* out = (float*)d_out;

    const int N = in_sizes[0] / F;   // 50000
    const int grid = (N + BR - 1) / BR;
    hipLaunchKernelGGL(fused_median_gemm, dim3(grid), dim3(TPB), 0, stream,
                       x, neigh, Ks, Kn, bias, out, N);
}

// Round 2
// 197.036 us; speedup vs baseline: 1.0315x; 1.0315x over previous
//
#include <hip/hip_runtime.h>

namespace {

typedef float f32x2 __attribute__((ext_vector_type(2)));
typedef float f32x4 __attribute__((ext_vector_type(4)));

constexpr int S   = 32;    // neighbors
constexpr int F   = 128;   // features
constexpr int BR  = 32;    // rows per block
constexpr int TPB = 256;

// ---- Batcher odd-even mergesort network for 16 elements (63 CEs) ----
struct CEPair { int a, b; };

constexpr int batcher_count16() {
  int n = 16, cnt = 0;
  for (int p = 1; p < n; p <<= 1)
    for (int k = p; k >= 1; k >>= 1)
      for (int j = k % p; j + k < n; j += 2 * k)
        for (int i = 0; i < k && i + j + k < n; ++i)
          if ((i + j) / (2 * p) == (i + j + k) / (2 * p))
            ++cnt;
  return cnt;
}
constexpr int NCE = batcher_count16();   // 63

struct Net16 { CEPair ce[NCE]; };

constexpr Net16 make_net16() {
  Net16 net{};
  int n = 16, c = 0;
  for (int p = 1; p < n; p <<= 1)
    for (int k = p; k >= 1; k >>= 1)
      for (int j = k % p; j + k < n; j += 2 * k)
        for (int i = 0; i < k && i + j + k < n; ++i)
          if ((i + j) / (2 * p) == (i + j + k) / (2 * p))
            net.ce[c++] = CEPair{i + j, i + j + k};
  return net;
}
constexpr Net16 NET16 = make_net16();

__device__ __forceinline__ f32x2 min2(f32x2 a, f32x2 b) {
  f32x2 r; r.x = fminf(a.x, b.x); r.y = fminf(a.y, b.y); return r;
}
__device__ __forceinline__ f32x2 max2(f32x2 a, f32x2 b) {
  f32x2 r; r.x = fmaxf(a.x, b.x); r.y = fmaxf(a.y, b.y); return r;
}

// compile-time-indexed application -> guaranteed registers (no scratch)
template<int T>
__device__ __forceinline__ void sort16(f32x2 (&v)[16]) {
  if constexpr (T < NCE) {
    constexpr int a = NET16.ce[T].a;
    constexpr int b = NET16.ce[T].b;
    f32x2 x = v[a], y = v[b];
    v[a] = min2(x, y);
    v[b] = max2(x, y);
    sort16<T + 1>(v);
  }
}

__global__ __launch_bounds__(TPB, 4) void fused_median_gemm(
    const float* __restrict__ x,
    const float* __restrict__ neigh,
    const float* __restrict__ Ks,
    const float* __restrict__ Kn,
    const float* __restrict__ bias,
    float* __restrict__ out,
    int N)
{
    __shared__ __align__(16) float xs[BR][F];   // staged x rows (16 KB)
    __shared__ __align__(16) float ms[BR][F];   // medians      (16 KB)

    const int tid  = threadIdx.x;
    const int row0 = blockIdx.x * BR;

    // ------------- Phase 1: rank-16-of-32 selection + x staging -------------
    {
        const int lane = tid & 63;             // feature-pair index (2 floats)
        const int rp   = tid >> 6;             // 0..3 row slot
#pragma unroll 1
        for (int i = 0; i < BR; i += 4) {
            const int rl = i + rp;
            int row = row0 + rl;
            if (row > N - 1) row = N - 1;      // clamp tail (harmless re-read)
            const f32x2* base =
                (const f32x2*)(neigh + (size_t)row * (S * F)) + lane;

            f32x2 A[16], B[16];
#pragma unroll
            for (int s = 0; s < 16; ++s)
                A[s] = __builtin_nontemporal_load(base + (size_t)s * 64);
#pragma unroll
            for (int s = 0; s < 16; ++s)
                B[s] = __builtin_nontemporal_load(base + (size_t)(16 + s) * 64);

            sort16<0>(A);                      // ascending
            sort16<0>(B);                      // ascending

            // rank-16 (0-indexed) of merge(A,B):
            //   med = min_{i=1..16} max(A[i-1], B[16-i])
            f32x2 c[16];
#pragma unroll
            for (int q = 0; q < 16; ++q) c[q] = max2(A[q], B[15 - q]);
#pragma unroll
            for (int st = 8; st >= 1; st >>= 1)
#pragma unroll
                for (int q = 0; q < st; ++q) c[q] = min2(c[q], c[q + st]);

            ((f32x2*)&ms[rl][0])[lane] = c[0];
            ((f32x2*)&xs[rl][0])[lane] =
                *((const f32x2*)(x + (size_t)row * F) + lane);
        }
    }
    __syncthreads();

    // ------------- Phase 2: dual GEMM (self | neigh), bias, relu -------------
    const int tu   = tid & 31;                 // output-col group: cols tu*8..+7
    const int tr   = tid >> 5;                 // 0..7 -> rows tr*4..+3
    const int ucol = tu * 8;
    const bool self_half = (tu < 16);
    const float* __restrict__ W = self_half ? Ks : Kn;
    const int ul = self_half ? ucol : (ucol - 128);
    const float* lin = self_half ? &xs[0][0] : &ms[0][0];

    f32x4 acc[4][2];
#pragma unroll
    for (int r = 0; r < 4; ++r) {
        acc[r][0] = f32x4{0.f, 0.f, 0.f, 0.f};
        acc[r][1] = f32x4{0.f, 0.f, 0.f, 0.f};
    }

    for (int f0 = 0; f0 < F; f0 += 4) {
        f32x4 wv[4][2];
#pragma unroll
        for (int df = 0; df < 4; ++df) {
            wv[df][0] = *(const f32x4*)&W[(f0 + df) * 128 + ul];
            wv[df][1] = *(const f32x4*)&W[(f0 + df) * 128 + ul + 4];
        }
        f32x4 xv[4];
#pragma unroll
        for (int r = 0; r < 4; ++r)
            xv[r] = *(const f32x4*)&lin[(tr * 4 + r) * F + f0];

#pragma unroll
        for (int r = 0; r < 4; ++r) {
#pragma unroll
            for (int df = 0; df < 4; ++df) {
                const float xc = xv[r][df];
#pragma unroll
                for (int h = 0; h < 2; ++h) {
                    acc[r][h].x = fmaf(xc, wv[df][h].x, acc[r][h].x);
                    acc[r][h].y = fmaf(xc, wv[df][h].y, acc[r][h].y);
                    acc[r][h].z = fmaf(xc, wv[df][h].z, acc[r][h].z);
                    acc[r][h].w = fmaf(xc, wv[df][h].w, acc[r][h].w);
                }
            }
        }
    }

    const f32x4 bv0 = *(const f32x4*)&bias[ucol];
    const f32x4 bv1 = *(const f32x4*)&bias[ucol + 4];
#pragma unroll
    for (int r = 0; r < 4; ++r) {
        const int row = row0 + tr * 4 + r;
        if (row < N) {
            f32x4 o0, o1;
            o0.x = fmaxf(acc[r][0].x + bv0.x, 0.f);
            o0.y = fmaxf(acc[r][0].y + bv0.y, 0.f);
            o0.z = fmaxf(acc[r][0].z + bv0.z, 0.f);
            o0.w = fmaxf(acc[r][0].w + bv0.w, 0.f);
            o1.x = fmaxf(acc[r][1].x + bv1.x, 0.f);
            o1.y = fmaxf(acc[r][1].y + bv1.y, 0.f);
            o1.z = fmaxf(acc[r][1].z + bv1.z, 0.f);
            o1.w = fmaxf(acc[r][1].w + bv1.w, 0.f);
            __builtin_nontemporal_store(o0, (f32x4*)&out[(size_t)row * 256 + ucol]);
            __builtin_nontemporal_store(o1, (f32x4*)&out[(size_t)row * 256 + ucol + 4]);
        }
    }
}

} // namespace

extern "C" void kernel_launch(void* const* d_in, const int* in_sizes, int n_in,
                              void* d_out, int out_size, void* d_ws, size_t ws_size,
                              hipStream_t stream) {
    const float* x     = (const float*)d_in[0];
    const float* neigh = (const float*)d_in[1];
    const float* Ks    = (const float*)d_in[2];
    const float* Kn    = (const float*)d_in[3];
    const float* bias  = (const float*)d_in[4];
    float* out = (float*)d_out;

    const int N = in_sizes[0] / F;   // 50000
    const int grid = (N + BR - 1) / BR;
    hipLaunchKernelGGL(fused_median_gemm, dim3(grid), dim3(TPB), 0, stream,
                       x, neigh, Ks, Kn, bias, out, N);
}